// Round 13
// baseline (359.096 us; speedup 1.0000x reference)
//
#include <hip/hip_runtime.h>
#include <stdint.h>

typedef unsigned short u16;
typedef float    f32x4 __attribute__((ext_vector_type(4)));
typedef _Float16 f16x8 __attribute__((ext_vector_type(8)));
typedef _Float16 f16x4 __attribute__((ext_vector_type(4)));

__device__ __forceinline__ u16 f2h(float f) {
  _Float16 h = (_Float16)f;  // v_cvt_f16_f32, RNE
  u16 u; __builtin_memcpy(&u, &h, 2); return u;
}
__device__ __forceinline__ float h2f(u16 u) {
  _Float16 h; __builtin_memcpy(&h, &u, 2); return (float)h;
}

__device__ __forceinline__ void mfma_f16(f32x4& c, f16x8 a, f16x8 b) {
  c = __builtin_amdgcn_mfma_f32_16x16x32_f16(a, b, c, 0, 0, 0);
}

// async global->LDS, 16B/lane; LDS dest = wave-uniform base, lane i lands at +i*16B
__device__ __forceinline__ void g2l16(const u16* g, u16* l) {
  __builtin_amdgcn_global_load_lds((const __attribute__((address_space(1))) void*)g,
                                   (__attribute__((address_space(3))) void*)l,
                                   16, 0, 0);
}

// generic XCD-chunk swizzle (grid product % 8 == 0 for all our grids)
__device__ __forceinline__ void xcd_swz(int& bx, int& by, int& bz) {
  const int gx = gridDim.x, gy = gridDim.y;
  const int n = gx * gy * gridDim.z;
  const int lin = blockIdx.x + gx * (blockIdx.y + gy * blockIdx.z);
  const int q = n >> 3;
  const int s = (lin & 7) * q + (lin >> 3);
  bx = s % gx;
  const int t2 = s / gx;
  by = t2 % gy;
  bz = t2 / gy;
}

struct alignas(8) US4 { u16 a, b, c, d; };

// ================= merged conversions =================
// grid (32, 32, 16), block (32, 8):
//   z 0..7  : conv_T sent batch z          (R=1024)
//   z 8..11 : conv_T tmpl, 2 batches per z (R=512)
//   z 12..15: flat grid-stride hilo(out) + f16(weights)
__global__ __launch_bounds__(256)
void k_conv_all(const float* __restrict__ out_f, const float* __restrict__ sent_f,
                const float* __restrict__ tmpl_f,
                const float* __restrict__ wg_f, const float* __restrict__ ws_f,
                const float* __restrict__ wt_f, const float* __restrict__ wo_f,
                u16* __restrict__ out_h, u16* __restrict__ out_lo,
                u16* __restrict__ sent_h, u16* __restrict__ sent_lo, u16* __restrict__ sentT,
                u16* __restrict__ tmpl_h, u16* __restrict__ tmpl_lo, u16* __restrict__ tmplT,
                u16* __restrict__ wg_h, u16* __restrict__ ws_h,
                u16* __restrict__ wt_h, u16* __restrict__ wo_h)
{
  __shared__ u16 t[32][33];
  const int z = blockIdx.z;
  const int tx = threadIdx.x, ty = threadIdx.y;
  constexpr int C = 1024;

  if (z < 12) {
    const float* src; u16 *dh, *dl, *dt; int R, b, r0;
    if (z < 8) {
      src = sent_f; dh = sent_h; dl = sent_lo; dt = sentT; R = 1024;
      b = z; r0 = blockIdx.y * 32;
    } else {
      src = tmpl_f; dh = tmpl_h; dl = tmpl_lo; dt = tmplT; R = 512;
      b = (z - 8) * 2 + (blockIdx.y >= 16); r0 = (blockIdx.y & 15) * 32;
    }
    const float* s = src + (size_t)b * R * C;
    u16* dhb = dh + (size_t)b * R * C;
    u16* dlb = dl + (size_t)b * R * C;
    u16* dtb = dt + (size_t)b * R * C;
    const int c0 = blockIdx.x * 32;
#pragma unroll
    for (int j = ty; j < 32; j += 8) {
      const size_t idx = (size_t)(r0 + j) * C + (c0 + tx);
      float x = s[idx];
      u16 h = f2h(x);
      dhb[idx] = h;
      dlb[idx] = f2h(x - h2f(h));
      t[j][tx] = h;
    }
    __syncthreads();
#pragma unroll
    for (int j = ty; j < 32; j += 8)
      dtb[(size_t)(c0 + j) * R + (r0 + tx)] = t[tx][j];
  } else {
    constexpr int N0 = 2097152;   // out: 8*1024*1024/4
    constexpr int N1 = 786432;    // Wg:  3*1024*1024/4
    constexpr int N2 = 262144;    // each 1024*1024/4
    constexpr int total = N0 + N1 + 3 * N2;
    const int blk = blockIdx.x + 32 * blockIdx.y + 1024 * (z - 12);
    int i = blk * 256 + (ty * 32 + tx);
    const int stride = 4096 * 256;
    for (; i < total; i += stride) {
      if (i < N0) {
        float4 v = reinterpret_cast<const float4*>(out_f)[i];
        US4 h, l;
        h.a = f2h(v.x); l.a = f2h(v.x - h2f(h.a));
        h.b = f2h(v.y); l.b = f2h(v.y - h2f(h.b));
        h.c = f2h(v.z); l.c = f2h(v.z - h2f(h.c));
        h.d = f2h(v.w); l.d = f2h(v.w - h2f(h.d));
        reinterpret_cast<US4*>(out_h)[i] = h;
        reinterpret_cast<US4*>(out_lo)[i] = l;
      } else {
        const float* s; u16* d; int j = i - N0;
        if (j < N1)                { s = wg_f; d = wg_h; }
        else if (j < N1 + N2)      { s = ws_f; d = ws_h; j -= N1; }
        else if (j < N1 + 2 * N2)  { s = wt_f; d = wt_h; j -= N1 + N2; }
        else                       { s = wo_f; d = wo_h; j -= N1 + 2 * N2; }
        float4 v = reinterpret_cast<const float4*>(s)[j];
        US4 h; h.a = f2h(v.x); h.b = f2h(v.y); h.c = f2h(v.z); h.d = f2h(v.w);
        reinterpret_cast<US4*>(d)[j] = h;
      }
    }
  }
}

// ================= merged softmax =================
template<int L>
__device__ __forceinline__ void sm_body(float* __restrict__ io, u16* __restrict__ pb, int bid) {
  const int lane = threadIdx.x & 63;
  const size_t r = (size_t)bid * 4 + (threadIdx.x >> 6);
  float* row = io + r * L;
  u16* prow = pb + r * L;
  constexpr int NV = L / 64;
  float v[NV];
  float mx = -3.4e38f;
#pragma unroll
  for (int j = 0; j < NV; ++j) { v[j] = row[lane + j * 64]; mx = fmaxf(mx, v[j]); }
#pragma unroll
  for (int s = 32; s; s >>= 1) mx = fmaxf(mx, __shfl_xor(mx, s));
  float sum = 0.f;
#pragma unroll
  for (int j = 0; j < NV; ++j) { v[j] = __expf(v[j] - mx); sum += v[j]; }
#pragma unroll
  for (int s = 32; s; s >>= 1) sum += __shfl_xor(sum, s);
  const float inv = 1.f / sum;
#pragma unroll
  for (int j = 0; j < NV; ++j) {
    float pv = v[j] * inv;
    row[lane + j * 64] = pv;
    prow[lane + j * 64] = f2h(pv);
  }
}

__global__ __launch_bounds__(256)
void k_softmax_all(float* __restrict__ sw, u16* __restrict__ Ps,
                   float* __restrict__ tw, u16* __restrict__ Pt) {
  if (blockIdx.x < 2048) sm_body<1024>(sw, Ps, blockIdx.x);
  else                   sm_body<512>(tw, Pt, blockIdx.x - 2048);
}

// ================= GEMM cores (BM=BN=128, 4 waves 2x2, 64x64 per wave) =================
struct TC { int wv, sr, sc, wm, wn, fr, kq; };

__device__ __forceinline__ TC make_tc(int tid) {
  TC t;
  const int lane = tid & 63;
  t.wv = tid >> 6;
  t.sr = lane >> 2;
  t.sc = (lane & 3) * 8;
  t.wm = t.wv >> 1;
  t.wn = t.wv & 1;
  t.fr = lane & 15;
  t.kq = (lane >> 4) * 8;
  return t;
}

constexpr int SUB = 128 * 32;   // one [128][32] sub-tile (8 KB)

// ---- pass64: 2-phase dbuf, BK=64 as two [128][32] sub-tiles ----
__device__ __forceinline__ void pass64(
    f32x4 (&acc)[16],
    const u16* __restrict__ A, int lda,
    const u16* __restrict__ B, int ldb,
    int K, u16* sA, u16* sB, const TC& t)
{
  const int nt = K / 64;
  auto stage = [&](int c, int k0) {
#pragma unroll
    for (int sub = 0; sub < 2; ++sub) {
      u16* dA = sA + c * (2 * SUB) + sub * SUB;
      u16* dB = sB + c * (2 * SUB) + sub * SUB;
      const u16* ar = A + (size_t)t.sr * lda + k0 + sub * 32 + t.sc;
      const u16* br = B + (size_t)t.sr * ldb + k0 + sub * 32 + t.sc;
      g2l16(ar + (size_t)(t.wv * 16) * lda, dA + (t.wv * 16) * 32);
      g2l16(ar + (size_t)((t.wv + 4) * 16) * lda, dA + ((t.wv + 4) * 16) * 32);
      g2l16(br + (size_t)(t.wv * 16) * ldb, dB + (t.wv * 16) * 32);
      g2l16(br + (size_t)((t.wv + 4) * 16) * ldb, dB + ((t.wv + 4) * 16) * 32);
    }
  };

  stage(0, 0);
  __syncthreads();
  int c = 0;
  for (int it = 0; it < nt; ++it) {
    if (it + 1 < nt) stage(c ^ 1, (it + 1) * 64);
#pragma unroll
    for (int sub = 0; sub < 2; ++sub) {
      const u16* bA = sA + c * (2 * SUB) + sub * SUB;
      const u16* bB = sB + c * (2 * SUB) + sub * SUB;
      f16x8 ah[4], bh[4];
#pragma unroll
      for (int i = 0; i < 4; ++i) {
        ah[i] = *reinterpret_cast<const f16x8*>(&bA[(t.wm * 64 + i * 16 + t.fr) * 32 + t.kq]);
        bh[i] = *reinterpret_cast<const f16x8*>(&bB[(t.wn * 64 + i * 16 + t.fr) * 32 + t.kq]);
      }
#pragma unroll
      for (int i = 0; i < 4; ++i)
#pragma unroll
        for (int j = 0; j < 4; ++j)
          mfma_f16(acc[i * 4 + j], ah[i], bh[j]);
    }
    __syncthreads();
    c ^= 1;
  }
}

// ---- pass32s: hi/lo split (3 MFMA/frag), 2-phase dbuf, BK=32 ----
__device__ __forceinline__ void pass32s(
    f32x4 (&acc)[16],
    const u16* __restrict__ A, const u16* __restrict__ Al, int lda,
    const u16* __restrict__ B, const u16* __restrict__ Bl, int ldb,
    int K, u16* sA, u16* sAl, u16* sB, u16* sBl, const TC& t)
{
  const int nt = K / 32;
  auto stage = [&](int c, int k0) {
    u16* dA = sA + c * SUB;  u16* dB = sB + c * SUB;
    u16* dAl = sAl + c * SUB; u16* dBl = sBl + c * SUB;
    const u16* ar = A + (size_t)t.sr * lda + k0 + t.sc;
    const u16* br = B + (size_t)t.sr * ldb + k0 + t.sc;
    const u16* alr = Al + (size_t)t.sr * lda + k0 + t.sc;
    const u16* blr = Bl + (size_t)t.sr * ldb + k0 + t.sc;
    g2l16(ar + (size_t)(t.wv * 16) * lda, dA + (t.wv * 16) * 32);
    g2l16(ar + (size_t)((t.wv + 4) * 16) * lda, dA + ((t.wv + 4) * 16) * 32);
    g2l16(br + (size_t)(t.wv * 16) * ldb, dB + (t.wv * 16) * 32);
    g2l16(br + (size_t)((t.wv + 4) * 16) * ldb, dB + ((t.wv + 4) * 16) * 32);
    g2l16(alr + (size_t)(t.wv * 16) * lda, dAl + (t.wv * 16) * 32);
    g2l16(alr + (size_t)((t.wv + 4) * 16) * lda, dAl + ((t.wv + 4) * 16) * 32);
    g2l16(blr + (size_t)(t.wv * 16) * ldb, dBl + (t.wv * 16) * 32);
    g2l16(blr + (size_t)((t.wv + 4) * 16) * ldb, dBl + ((t.wv + 4) * 16) * 32);
  };

  stage(0, 0);
  __syncthreads();
  int c = 0;
  for (int it = 0; it < nt; ++it) {
    if (it + 1 < nt) stage(c ^ 1, (it + 1) * 32);
    const u16* bA = sA + c * SUB;  const u16* bB = sB + c * SUB;
    const u16* bAl = sAl + c * SUB; const u16* bBl = sBl + c * SUB;
    f16x8 ah[4], bh[4], al[4], bl[4];
#pragma unroll
    for (int i = 0; i < 4; ++i) {
      ah[i] = *reinterpret_cast<const f16x8*>(&bA[(t.wm * 64 + i * 16 + t.fr) * 32 + t.kq]);
      bh[i] = *reinterpret_cast<const f16x8*>(&bB[(t.wn * 64 + i * 16 + t.fr) * 32 + t.kq]);
      al[i] = *reinterpret_cast<const f16x8*>(&bAl[(t.wm * 64 + i * 16 + t.fr) * 32 + t.kq]);
      bl[i] = *reinterpret_cast<const f16x8*>(&bBl[(t.wn * 64 + i * 16 + t.fr) * 32 + t.kq]);
    }
#pragma unroll
    for (int i = 0; i < 4; ++i)
#pragma unroll
      for (int j = 0; j < 4; ++j) {
        mfma_f16(acc[i * 4 + j], ah[i], bh[j]);
        mfma_f16(acc[i * 4 + j], al[i], bh[j]);
        mfma_f16(acc[i * 4 + j], ah[i], bl[j]);
      }
    __syncthreads();
    c ^= 1;
  }
}

// ---- pass32d: ONE A staged, TWO B targets, 2-phase dbuf ----
__device__ __forceinline__ void pass32d(
    f32x4 (&accZ)[16], f32x4 (&accW)[16],
    const u16* __restrict__ A, int lda,
    const u16* __restrict__ B0, int ldb0,
    const u16* __restrict__ B1, int ldb1,
    int K, u16* sA, u16* sB0, u16* sB1, const TC& t)
{
  const int nt = K / 32;
  auto stage = [&](int c, int k0) {
    u16* dA = sA + c * SUB;
    u16* d0 = sB0 + c * SUB;
    u16* d1 = sB1 + c * SUB;
    const u16* ar = A + (size_t)t.sr * lda + k0 + t.sc;
    const u16* b0 = B0 + (size_t)t.sr * ldb0 + k0 + t.sc;
    const u16* b1 = B1 + (size_t)t.sr * ldb1 + k0 + t.sc;
    g2l16(ar + (size_t)(t.wv * 16) * lda, dA + (t.wv * 16) * 32);
    g2l16(ar + (size_t)((t.wv + 4) * 16) * lda, dA + ((t.wv + 4) * 16) * 32);
    g2l16(b0 + (size_t)(t.wv * 16) * ldb0, d0 + (t.wv * 16) * 32);
    g2l16(b0 + (size_t)((t.wv + 4) * 16) * ldb0, d0 + ((t.wv + 4) * 16) * 32);
    g2l16(b1 + (size_t)(t.wv * 16) * ldb1, d1 + (t.wv * 16) * 32);
    g2l16(b1 + (size_t)((t.wv + 4) * 16) * ldb1, d1 + ((t.wv + 4) * 16) * 32);
  };

  stage(0, 0);
  __syncthreads();
  int c = 0;
  for (int it = 0; it < nt; ++it) {
    if (it + 1 < nt) stage(c ^ 1, (it + 1) * 32);
    const u16* bA = sA + c * SUB;
    f16x8 ah[4];
#pragma unroll
    for (int i = 0; i < 4; ++i)
      ah[i] = *reinterpret_cast<const f16x8*>(&bA[(t.wm * 64 + i * 16 + t.fr) * 32 + t.kq]);
    {
      const u16* b0 = sB0 + c * SUB;
      f16x8 bh[4];
#pragma unroll
      for (int j = 0; j < 4; ++j)
        bh[j] = *reinterpret_cast<const f16x8*>(&b0[(t.wn * 64 + j * 16 + t.fr) * 32 + t.kq]);
#pragma unroll
      for (int i = 0; i < 4; ++i)
#pragma unroll
        for (int j = 0; j < 4; ++j)
          mfma_f16(accZ[i * 4 + j], ah[i], bh[j]);
    }
    {
      const u16* b1 = sB1 + c * SUB;
      f16x8 bh[4];
#pragma unroll
      for (int j = 0; j < 4; ++j)
        bh[j] = *reinterpret_cast<const f16x8*>(&b1[(t.wn * 64 + j * 16 + t.fr) * 32 + t.kq]);
#pragma unroll
      for (int i = 0; i < 4; ++i)
#pragma unroll
        for (int j = 0; j < 4; ++j)
          mfma_f16(accW[i * 4 + j], ah[i], bh[j]);
    }
    __syncthreads();
    c ^= 1;
  }
}

// ---- merged logits: grid (8, 8, 12) ----
//   bz 0..7 : sent (col-tile bx 0..7), batch bz
//   bz 8..11: tmpl, batch (bz-8)*2 + (bx>>2), col-tile bx&3
__global__ __launch_bounds__(256, 2)
void k_logits_all(const u16* __restrict__ Ah, const u16* __restrict__ Al,
                  const u16* __restrict__ sentBh, const u16* __restrict__ sentBl,
                  const u16* __restrict__ tmplBh, const u16* __restrict__ tmplBl,
                  float* __restrict__ sw, float* __restrict__ tw)
{
  __shared__ __align__(16) u16 ldsA[2 * SUB], ldsB[2 * SUB], ldsAl[2 * SUB], ldsBl[2 * SUB];
  int bx, by, bz;
  xcd_swz(bx, by, bz);
  const TC t = make_tc(threadIdx.x);

  const u16 *Bh, *Bl; float* Cf; int ldc, b, colTile;
  if (bz < 8) {
    b = bz; colTile = bx; Bh = sentBh; Bl = sentBl; Cf = sw; ldc = 1024;
  } else {
    b = (bz - 8) * 2 + (bx >> 2); colTile = bx & 3; Bh = tmplBh; Bl = tmplBl; Cf = tw; ldc = 512;
  }
  const size_t aoff = (size_t)b * (1024 * 1024) + (size_t)by * 128 * 1024;
  const size_t boff = (size_t)b * ((size_t)ldc * 1024) + (size_t)colTile * 128 * 1024;

  f32x4 acc[16];
#pragma unroll
  for (int i = 0; i < 16; ++i) acc[i] = f32x4{0.f, 0.f, 0.f, 0.f};

  pass32s(acc, Ah + aoff, Al + aoff, 1024, Bh + boff, Bl + boff, 1024, 1024,
          ldsA, ldsAl, ldsB, ldsBl, t);

  const size_t cbse = (size_t)b * (1024 * (size_t)ldc);
  const int row0 = by * 128 + t.wm * 64;
  const int col0 = colTile * 128 + t.wn * 64;
  const int fq = ((threadIdx.x & 63) >> 4) * 4;
#pragma unroll
  for (int i = 0; i < 4; ++i)
#pragma unroll
    for (int j = 0; j < 4; ++j) {
      const int c = col0 + j * 16 + t.fr;
#pragma unroll
      for (int q = 0; q < 4; ++q)
        Cf[cbse + (size_t)(row0 + i * 16 + fq + q) * ldc + c] = acc[i * 4 + j][q];
    }
}

// ---- merged PV: grid (8, 8, 16); bz<8 sent (K=1024), bz>=8 tmpl (K=512) ----
__global__ __launch_bounds__(256, 2)
void k_pv_all(const u16* __restrict__ Ps, const u16* __restrict__ sentT,
              const u16* __restrict__ Pt, const u16* __restrict__ tmplT,
              u16* __restrict__ ctx_s, u16* __restrict__ ctx_t)
{
  __shared__ __align__(16) u16 ldsA[2 * 2 * SUB], ldsB[2 * 2 * SUB];
  int bx, by, bz;
  xcd_swz(bx, by, bz);
  const TC t = make_tc(threadIdx.x);

  const u16 *A, *Bt; u16* Cb; int ld, b;
  if (bz < 8) { b = bz; A = Ps; Bt = sentT; Cb = ctx_s; ld = 1024; }
  else        { b = bz - 8; A = Pt; Bt = tmplT; Cb = ctx_t; ld = 512; }

  f32x4 acc[16];
#pragma unroll
  for (int i = 0; i < 16; ++i) acc[i] = f32x4{0.f, 0.f, 0.f, 0.f};

  pass64(acc, A + (size_t)b * 1024 * ld + (size_t)by * 128 * ld, ld,
         Bt + (size_t)b * 1024 * ld + (size_t)bx * 128 * ld, ld, ld, ldsA, ldsB, t);

  const size_t cbse = (size_t)b * (1024 * 1024);
  const int row0 = by * 128 + t.wm * 64;
  const int col0 = bx * 128 + t.wn * 64;
  const int fq = ((threadIdx.x & 63) >> 4) * 4;
#pragma unroll
  for (int i = 0; i < 4; ++i)
#pragma unroll
    for (int j = 0; j < 4; ++j) {
      const int c = col0 + j * 16 + t.fr;
#pragma unroll
      for (int q = 0; q < 4; ++q)
        Cb[cbse + (size_t)(row0 + i * 16 + fq + q) * 1024 + c] = f2h(acc[i * 4 + j][q]);
    }
}

// ---- fusion4: 3 dual passes (round-11 proven) ----
__global__ __launch_bounds__(256, 2)
void k_fusion4(const u16* __restrict__ ctx_s, const u16* __restrict__ ctx_t,
               const u16* __restrict__ outh,
               const u16* __restrict__ Wg, const u16* __restrict__ Ws,
               const u16* __restrict__ Wt, const u16* __restrict__ Wo,
               float* __restrict__ fus)
{
  constexpr int H = 1024;
  __shared__ __align__(16) u16 ldsA[2 * SUB], ldsB0[2 * SUB], ldsB1[2 * SUB];  // 48 KB

  int bx, by, bz;
  xcd_swz(bx, by, bz);           // grid (8, 64, 1)
  const TC t = make_tc(threadIdx.x);

  const size_t aoff = (size_t)by * 128 * H;
  const size_t wgoff = (size_t)bx * 128 * (3 * H);
  const int row0 = by * 128 + t.wm * 64;
  const int col0 = bx * 128 + t.wn * 64;
  const int fq = ((threadIdx.x & 63) >> 4) * 4;

  f32x4 accZ[16], accW[16];
#pragma unroll
  for (int i = 0; i < 16; ++i) {
    accZ[i] = f32x4{0.f, 0.f, 0.f, 0.f};
    accW[i] = f32x4{0.f, 0.f, 0.f, 0.f};
  }

  // pass 0: A = ctx_s, B0 = Wg seg0, B1 = Ws
  pass32d(accZ, accW, ctx_s + aoff, H, Wg + wgoff, 3 * H,
          Ws + (size_t)bx * 128 * H, H, H, ldsA, ldsB0, ldsB1, t);
  f16x4 S16[16];
#pragma unroll
  for (int f = 0; f < 16; ++f) {
#pragma unroll
    for (int q = 0; q < 4; ++q) S16[f][q] = (_Float16)accW[f][q];
    accW[f] = f32x4{0.f, 0.f, 0.f, 0.f};
  }

  // pass 1: A = ctx_t, B0 = Wg seg1, B1 = Wt
  pass32d(accZ, accW, ctx_t + aoff, H, Wg + wgoff + H, 3 * H,
          Wt + (size_t)bx * 128 * H, H, H, ldsA, ldsB0, ldsB1, t);
  f16x4 T16[16];
#pragma unroll
  for (int f = 0; f < 16; ++f) {
#pragma unroll
    for (int q = 0; q < 4; ++q) T16[f][q] = (_Float16)accW[f][q];
    accW[f] = f32x4{0.f, 0.f, 0.f, 0.f};
  }

  // pass 2: A = outh, B0 = Wg seg2, B1 = Wo
  pass32d(accZ, accW, outh + aoff, H, Wg + wgoff + 2 * H, 3 * H,
          Wo + (size_t)bx * 128 * H, H, H, ldsA, ldsB0, ldsB1, t);

  // epilogue: g = sigmoid(z); fus = tanh(S + g*(T-S) + O)
#pragma unroll
  for (int i = 0; i < 4; ++i)
#pragma unroll
    for (int j = 0; j < 4; ++j) {
      const int f = i * 4 + j;
      const int c = col0 + j * 16 + t.fr;
#pragma unroll
      for (int q = 0; q < 4; ++q) {
        const int r = row0 + i * 16 + fq + q;
        const float g = 1.f / (1.f + __expf(-accZ[f][q]));
        const float sv = (float)S16[f][q];
        const float tv = (float)T16[f][q];
        float x = sv + g * (tv - sv) + accW[f][q];
        float ax = fabsf(x);
        float e = __expf(-2.f * ax);
        float th = (1.f - e) / (1.f + e);
        fus[(size_t)r * H + c] = copysignf(th, x);
      }
    }
}

extern "C" void kernel_launch(void* const* d_in, const int* in_sizes, int n_in,
                              void* d_out, int out_size, void* d_ws, size_t ws_size,
                              hipStream_t stream) {
  (void)in_sizes; (void)n_in; (void)out_size; (void)ws_size;
  constexpr int B = 8, T = 1024, S = 1024, St = 512, H = 1024;
  constexpr long long BTH = (long long)B * T * H;
  constexpr long long BSH = (long long)B * S * H;
  constexpr long long BStH = (long long)B * St * H;
  constexpr long long BTS = (long long)B * T * S;
  constexpr long long BTSt = (long long)B * T * St;

  const float* in_out  = (const float*)d_in[0];
  const float* in_sent = (const float*)d_in[1];
  const float* in_tmpl = (const float*)d_in[2];
  const float* in_Wg   = (const float*)d_in[3];
  const float* in_Ws   = (const float*)d_in[4];
  const float* in_Wt   = (const float*)d_in[5];
  const float* in_Wo   = (const float*)d_in[6];

  float* fus = (float*)d_out;         // (B,T,H)
  float* sw  = fus + BTH;             // (B,T,S)
  float* tw  = sw + BTS;              // (B,T,St)

  // ---- workspace ----
  char* p = (char*)d_ws;
  auto take = [&](long long bytes) { char* q = p; p += bytes; return q; };
  u16* out_h   = (u16*)take(BTH * 2);
  u16* out_lo  = (u16*)take(BTH * 2);
  u16* sent_h  = (u16*)take(BSH * 2);    // dead after logits -> reused as ctx_s
  u16* sent_lo = (u16*)take(BSH * 2);    // dead after logits -> reused as ctx_t
  u16* tmpl_h  = (u16*)take(BStH * 2);
  u16* tmpl_lo = (u16*)take(BStH * 2);
  u16* sentT   = (u16*)take(BSH * 2);    // (B,H,S)
  u16* tmplT   = (u16*)take(BStH * 2);   // (B,H,St)
  u16* Wg_h    = (u16*)take((long long)3 * H * H * 2);
  u16* Ws_h    = (u16*)take((long long)H * H * 2);
  u16* Wt_h    = (u16*)take((long long)H * H * 2);
  u16* Wo_h    = (u16*)take((long long)H * H * 2);
  u16* Ps      = (u16*)take(BTS * 2);
  u16* Pt      = (u16*)take(BTSt * 2);

  u16* ctx_s = sent_h;
  u16* ctx_t = sent_lo;

  dim3 thr(256);

  // 1: all conversions
  k_conv_all<<<dim3(32, 32, 16), dim3(32, 8), 0, stream>>>(
      in_out, in_sent, in_tmpl, in_Wg, in_Ws, in_Wt, in_Wo,
      out_h, out_lo, sent_h, sent_lo, sentT, tmpl_h, tmpl_lo, tmplT,
      Wg_h, Ws_h, Wt_h, Wo_h);

  // 2: both logits (3-pass split f16) -> d_out weight slots
  k_logits_all<<<dim3(8, 8, 12), thr, 0, stream>>>(
      out_h, out_lo, sent_h, sent_lo, tmpl_h, tmpl_lo, sw, tw);

  // 3: both softmaxes (in place + f16 copy)
  k_softmax_all<<<4096, 256, 0, stream>>>(sw, Ps, tw, Pt);

  // 4: both PV GEMMs -> ctx (f16)
  k_pv_all<<<dim3(8, 8, 16), thr, 0, stream>>>(Ps, sentT, Pt, tmplT, ctx_s, ctx_t);

  // 5: fused gate + fusion (dual-B passes)
  k_fusion4<<<dim3(8, 64), thr, 0, stream>>>(
      ctx_s, ctx_t, out_h, Wg_h, Ws_h, Wt_h, Wo_h, fus);
}

// Round 14
// 346.373 us; speedup vs baseline: 1.0367x; 1.0367x over previous
//
#include <hip/hip_runtime.h>
#include <stdint.h>

typedef unsigned short u16;
typedef float    f32x4 __attribute__((ext_vector_type(4)));
typedef _Float16 f16x8 __attribute__((ext_vector_type(8)));
typedef _Float16 f16x4 __attribute__((ext_vector_type(4)));

__device__ __forceinline__ u16 f2h(float f) {
  _Float16 h = (_Float16)f;  // v_cvt_f16_f32, RNE
  u16 u; __builtin_memcpy(&u, &h, 2); return u;
}
__device__ __forceinline__ float h2f(u16 u) {
  _Float16 h; __builtin_memcpy(&h, &u, 2); return (float)h;
}

__device__ __forceinline__ void mfma_f16(f32x4& c, f16x8 a, f16x8 b) {
  c = __builtin_amdgcn_mfma_f32_16x16x32_f16(a, b, c, 0, 0, 0);
}

// async global->LDS, 16B/lane; LDS dest = wave-uniform base, lane i lands at +i*16B
__device__ __forceinline__ void g2l16(const u16* g, u16* l) {
  __builtin_amdgcn_global_load_lds((const __attribute__((address_space(1))) void*)g,
                                   (__attribute__((address_space(3))) void*)l,
                                   16, 0, 0);
}

// generic XCD-chunk swizzle (grid product % 8 == 0 for all our grids)
__device__ __forceinline__ void xcd_swz(int& bx, int& by, int& bz) {
  const int gx = gridDim.x, gy = gridDim.y;
  const int n = gx * gy * gridDim.z;
  const int lin = blockIdx.x + gx * (blockIdx.y + gy * blockIdx.z);
  const int q = n >> 3;
  const int s = (lin & 7) * q + (lin >> 3);
  bx = s % gx;
  const int t2 = s / gx;
  by = t2 % gy;
  bz = t2 / gy;
}

struct alignas(8) US4 { u16 a, b, c, d; };

// ================= merged conversions =================
// grid (32, 32, 16), block (32, 8):
//   z 0..7  : conv_T sent batch z          (R=1024)
//   z 8..11 : conv_T tmpl, 2 batches per z (R=512)
//   z 12..15: flat grid-stride hilo(out) + f16(weights)
__global__ __launch_bounds__(256)
void k_conv_all(const float* __restrict__ out_f, const float* __restrict__ sent_f,
                const float* __restrict__ tmpl_f,
                const float* __restrict__ wg_f, const float* __restrict__ ws_f,
                const float* __restrict__ wt_f, const float* __restrict__ wo_f,
                u16* __restrict__ out_h, u16* __restrict__ out_lo,
                u16* __restrict__ sent_h, u16* __restrict__ sent_lo, u16* __restrict__ sentT,
                u16* __restrict__ tmpl_h, u16* __restrict__ tmpl_lo, u16* __restrict__ tmplT,
                u16* __restrict__ wg_h, u16* __restrict__ ws_h,
                u16* __restrict__ wt_h, u16* __restrict__ wo_h)
{
  __shared__ u16 t[32][33];
  const int z = blockIdx.z;
  const int tx = threadIdx.x, ty = threadIdx.y;
  constexpr int C = 1024;

  if (z < 12) {
    const float* src; u16 *dh, *dl, *dt; int R, b, r0;
    if (z < 8) {
      src = sent_f; dh = sent_h; dl = sent_lo; dt = sentT; R = 1024;
      b = z; r0 = blockIdx.y * 32;
    } else {
      src = tmpl_f; dh = tmpl_h; dl = tmpl_lo; dt = tmplT; R = 512;
      b = (z - 8) * 2 + (blockIdx.y >= 16); r0 = (blockIdx.y & 15) * 32;
    }
    const float* s = src + (size_t)b * R * C;
    u16* dhb = dh + (size_t)b * R * C;
    u16* dlb = dl + (size_t)b * R * C;
    u16* dtb = dt + (size_t)b * R * C;
    const int c0 = blockIdx.x * 32;
#pragma unroll
    for (int j = ty; j < 32; j += 8) {
      const size_t idx = (size_t)(r0 + j) * C + (c0 + tx);
      float x = s[idx];
      u16 h = f2h(x);
      dhb[idx] = h;
      dlb[idx] = f2h(x - h2f(h));
      t[j][tx] = h;
    }
    __syncthreads();
#pragma unroll
    for (int j = ty; j < 32; j += 8)
      dtb[(size_t)(c0 + j) * R + (r0 + tx)] = t[tx][j];
  } else {
    constexpr int N0 = 2097152;   // out: 8*1024*1024/4
    constexpr int N1 = 786432;    // Wg:  3*1024*1024/4
    constexpr int N2 = 262144;    // each 1024*1024/4
    constexpr int total = N0 + N1 + 3 * N2;
    const int blk = blockIdx.x + 32 * blockIdx.y + 1024 * (z - 12);
    int i = blk * 256 + (ty * 32 + tx);
    const int stride = 4096 * 256;
    for (; i < total; i += stride) {
      if (i < N0) {
        float4 v = reinterpret_cast<const float4*>(out_f)[i];
        US4 h, l;
        h.a = f2h(v.x); l.a = f2h(v.x - h2f(h.a));
        h.b = f2h(v.y); l.b = f2h(v.y - h2f(h.b));
        h.c = f2h(v.z); l.c = f2h(v.z - h2f(h.c));
        h.d = f2h(v.w); l.d = f2h(v.w - h2f(h.d));
        reinterpret_cast<US4*>(out_h)[i] = h;
        reinterpret_cast<US4*>(out_lo)[i] = l;
      } else {
        const float* s; u16* d; int j = i - N0;
        if (j < N1)                { s = wg_f; d = wg_h; }
        else if (j < N1 + N2)      { s = ws_f; d = ws_h; j -= N1; }
        else if (j < N1 + 2 * N2)  { s = wt_f; d = wt_h; j -= N1 + N2; }
        else                       { s = wo_f; d = wo_h; j -= N1 + 2 * N2; }
        float4 v = reinterpret_cast<const float4*>(s)[j];
        US4 h; h.a = f2h(v.x); h.b = f2h(v.y); h.c = f2h(v.z); h.d = f2h(v.w);
        reinterpret_cast<US4*>(d)[j] = h;
      }
    }
  }
}

// ================= merged softmax =================
template<int L>
__device__ __forceinline__ void sm_body(float* __restrict__ io, u16* __restrict__ pb, int bid) {
  const int lane = threadIdx.x & 63;
  const size_t r = (size_t)bid * 4 + (threadIdx.x >> 6);
  float* row = io + r * L;
  u16* prow = pb + r * L;
  constexpr int NV = L / 64;
  float v[NV];
  float mx = -3.4e38f;
#pragma unroll
  for (int j = 0; j < NV; ++j) { v[j] = row[lane + j * 64]; mx = fmaxf(mx, v[j]); }
#pragma unroll
  for (int s = 32; s; s >>= 1) mx = fmaxf(mx, __shfl_xor(mx, s));
  float sum = 0.f;
#pragma unroll
  for (int j = 0; j < NV; ++j) { v[j] = __expf(v[j] - mx); sum += v[j]; }
#pragma unroll
  for (int s = 32; s; s >>= 1) sum += __shfl_xor(sum, s);
  const float inv = 1.f / sum;
#pragma unroll
  for (int j = 0; j < NV; ++j) {
    float pv = v[j] * inv;
    row[lane + j * 64] = pv;
    prow[lane + j * 64] = f2h(pv);
  }
}

__global__ __launch_bounds__(256)
void k_softmax_all(float* __restrict__ sw, u16* __restrict__ Ps,
                   float* __restrict__ tw, u16* __restrict__ Pt) {
  if (blockIdx.x < 2048) sm_body<1024>(sw, Ps, blockIdx.x);
  else                   sm_body<512>(tw, Pt, blockIdx.x - 2048);
}

// ================= GEMM cores =================
struct TC { int wv, sr, sc, wm, wn, fr, kq; };

__device__ __forceinline__ TC make_tc(int tid) {
  TC t;
  const int lane = tid & 63;
  t.wv = tid >> 6;
  t.sr = lane >> 2;
  t.sc = (lane & 3) * 8;
  t.wm = t.wv >> 1;
  t.wn = t.wv & 1;
  t.fr = lane & 15;
  t.kq = (lane >> 4) * 8;
  return t;
}

constexpr int SUB = 128 * 32;    // [128][32] sub-tile (8 KB)
constexpr int SUB64 = 64 * 32;   // [64][32] sub-tile (4 KB)

// ---- pass64: 2-phase dbuf, BK=64 as two [128][32] sub-tiles (BM=BN=128) ----
__device__ __forceinline__ void pass64(
    f32x4 (&acc)[16],
    const u16* __restrict__ A, int lda,
    const u16* __restrict__ B, int ldb,
    int K, u16* sA, u16* sB, const TC& t)
{
  const int nt = K / 64;
  auto stage = [&](int c, int k0) {
#pragma unroll
    for (int sub = 0; sub < 2; ++sub) {
      u16* dA = sA + c * (2 * SUB) + sub * SUB;
      u16* dB = sB + c * (2 * SUB) + sub * SUB;
      const u16* ar = A + (size_t)t.sr * lda + k0 + sub * 32 + t.sc;
      const u16* br = B + (size_t)t.sr * ldb + k0 + sub * 32 + t.sc;
      g2l16(ar + (size_t)(t.wv * 16) * lda, dA + (t.wv * 16) * 32);
      g2l16(ar + (size_t)((t.wv + 4) * 16) * lda, dA + ((t.wv + 4) * 16) * 32);
      g2l16(br + (size_t)(t.wv * 16) * ldb, dB + (t.wv * 16) * 32);
      g2l16(br + (size_t)((t.wv + 4) * 16) * ldb, dB + ((t.wv + 4) * 16) * 32);
    }
  };

  stage(0, 0);
  __syncthreads();
  int c = 0;
  for (int it = 0; it < nt; ++it) {
    if (it + 1 < nt) stage(c ^ 1, (it + 1) * 64);
#pragma unroll
    for (int sub = 0; sub < 2; ++sub) {
      const u16* bA = sA + c * (2 * SUB) + sub * SUB;
      const u16* bB = sB + c * (2 * SUB) + sub * SUB;
      f16x8 ah[4], bh[4];
#pragma unroll
      for (int i = 0; i < 4; ++i) {
        ah[i] = *reinterpret_cast<const f16x8*>(&bA[(t.wm * 64 + i * 16 + t.fr) * 32 + t.kq]);
        bh[i] = *reinterpret_cast<const f16x8*>(&bB[(t.wn * 64 + i * 16 + t.fr) * 32 + t.kq]);
      }
#pragma unroll
      for (int i = 0; i < 4; ++i)
#pragma unroll
        for (int j = 0; j < 4; ++j)
          mfma_f16(acc[i * 4 + j], ah[i], bh[j]);
    }
    __syncthreads();
    c ^= 1;
  }
}

// ---- pass32s64: hi/lo split (3 MFMA/frag), BM=128, BN=64, 2-phase dbuf ----
// LDS: sA/sAl = 2*SUB (16 KB each), sB/sBl = 2*SUB64 (8 KB each) => 48 KB total.
__device__ __forceinline__ void pass32s64(
    f32x4 (&acc)[8],
    const u16* __restrict__ A, const u16* __restrict__ Al, int lda,
    const u16* __restrict__ B, const u16* __restrict__ Bl, int ldb,
    int K, u16* sA, u16* sAl, u16* sB, u16* sBl, const TC& t)
{
  const int nt = K / 32;
  auto stage = [&](int c, int k0) {
    u16* dA  = sA  + c * SUB;
    u16* dAl = sAl + c * SUB;
    u16* dB  = sB  + c * SUB64;
    u16* dBl = sBl + c * SUB64;
    const u16* ar  = A  + (size_t)t.sr * lda + k0 + t.sc;
    const u16* alr = Al + (size_t)t.sr * lda + k0 + t.sc;
    const u16* br  = B  + (size_t)t.sr * ldb + k0 + t.sc;
    const u16* blr = Bl + (size_t)t.sr * ldb + k0 + t.sc;
    g2l16(ar  + (size_t)(t.wv * 16) * lda, dA  + (t.wv * 16) * 32);
    g2l16(ar  + (size_t)((t.wv + 4) * 16) * lda, dA  + ((t.wv + 4) * 16) * 32);
    g2l16(alr + (size_t)(t.wv * 16) * lda, dAl + (t.wv * 16) * 32);
    g2l16(alr + (size_t)((t.wv + 4) * 16) * lda, dAl + ((t.wv + 4) * 16) * 32);
    g2l16(br  + (size_t)(t.wv * 16) * ldb, dB  + (t.wv * 16) * 32);
    g2l16(blr + (size_t)(t.wv * 16) * ldb, dBl + (t.wv * 16) * 32);
  };

  stage(0, 0);
  __syncthreads();
  int c = 0;
  for (int it = 0; it < nt; ++it) {
    if (it + 1 < nt) stage(c ^ 1, (it + 1) * 32);
    const u16* bA  = sA  + c * SUB;
    const u16* bAl = sAl + c * SUB;
    const u16* bB  = sB  + c * SUB64;
    const u16* bBl = sBl + c * SUB64;
    f16x8 ah[4], al[4], bh[2], bl[2];
#pragma unroll
    for (int i = 0; i < 4; ++i) {
      ah[i] = *reinterpret_cast<const f16x8*>(&bA [(t.wm * 64 + i * 16 + t.fr) * 32 + t.kq]);
      al[i] = *reinterpret_cast<const f16x8*>(&bAl[(t.wm * 64 + i * 16 + t.fr) * 32 + t.kq]);
    }
#pragma unroll
    for (int j = 0; j < 2; ++j) {
      bh[j] = *reinterpret_cast<const f16x8*>(&bB [(t.wn * 32 + j * 16 + t.fr) * 32 + t.kq]);
      bl[j] = *reinterpret_cast<const f16x8*>(&bBl[(t.wn * 32 + j * 16 + t.fr) * 32 + t.kq]);
    }
#pragma unroll
    for (int i = 0; i < 4; ++i)
#pragma unroll
      for (int j = 0; j < 2; ++j) {
        mfma_f16(acc[i * 2 + j], ah[i], bh[j]);
        mfma_f16(acc[i * 2 + j], al[i], bh[j]);
        mfma_f16(acc[i * 2 + j], ah[i], bl[j]);
      }
    __syncthreads();
    c ^= 1;
  }
}

// ---- pass32d: ONE A staged, TWO B targets, 2-phase dbuf (BM=BN=128) ----
__device__ __forceinline__ void pass32d(
    f32x4 (&accZ)[16], f32x4 (&accW)[16],
    const u16* __restrict__ A, int lda,
    const u16* __restrict__ B0, int ldb0,
    const u16* __restrict__ B1, int ldb1,
    int K, u16* sA, u16* sB0, u16* sB1, const TC& t)
{
  const int nt = K / 32;
  auto stage = [&](int c, int k0) {
    u16* dA = sA + c * SUB;
    u16* d0 = sB0 + c * SUB;
    u16* d1 = sB1 + c * SUB;
    const u16* ar = A + (size_t)t.sr * lda + k0 + t.sc;
    const u16* b0 = B0 + (size_t)t.sr * ldb0 + k0 + t.sc;
    const u16* b1 = B1 + (size_t)t.sr * ldb1 + k0 + t.sc;
    g2l16(ar + (size_t)(t.wv * 16) * lda, dA + (t.wv * 16) * 32);
    g2l16(ar + (size_t)((t.wv + 4) * 16) * lda, dA + ((t.wv + 4) * 16) * 32);
    g2l16(b0 + (size_t)(t.wv * 16) * ldb0, d0 + (t.wv * 16) * 32);
    g2l16(b0 + (size_t)((t.wv + 4) * 16) * ldb0, d0 + ((t.wv + 4) * 16) * 32);
    g2l16(b1 + (size_t)(t.wv * 16) * ldb1, d1 + (t.wv * 16) * 32);
    g2l16(b1 + (size_t)((t.wv + 4) * 16) * ldb1, d1 + ((t.wv + 4) * 16) * 32);
  };

  stage(0, 0);
  __syncthreads();
  int c = 0;
  for (int it = 0; it < nt; ++it) {
    if (it + 1 < nt) stage(c ^ 1, (it + 1) * 32);
    const u16* bA = sA + c * SUB;
    f16x8 ah[4];
#pragma unroll
    for (int i = 0; i < 4; ++i)
      ah[i] = *reinterpret_cast<const f16x8*>(&bA[(t.wm * 64 + i * 16 + t.fr) * 32 + t.kq]);
    {
      const u16* b0 = sB0 + c * SUB;
      f16x8 bh[4];
#pragma unroll
      for (int j = 0; j < 4; ++j)
        bh[j] = *reinterpret_cast<const f16x8*>(&b0[(t.wn * 64 + j * 16 + t.fr) * 32 + t.kq]);
#pragma unroll
      for (int i = 0; i < 4; ++i)
#pragma unroll
        for (int j = 0; j < 4; ++j)
          mfma_f16(accZ[i * 4 + j], ah[i], bh[j]);
    }
    {
      const u16* b1 = sB1 + c * SUB;
      f16x8 bh[4];
#pragma unroll
      for (int j = 0; j < 4; ++j)
        bh[j] = *reinterpret_cast<const f16x8*>(&b1[(t.wn * 64 + j * 16 + t.fr) * 32 + t.kq]);
#pragma unroll
      for (int i = 0; i < 4; ++i)
#pragma unroll
        for (int j = 0; j < 4; ++j)
          mfma_f16(accW[i * 4 + j], ah[i], bh[j]);
    }
    __syncthreads();
    c ^= 1;
  }
}

// ---- merged logits, BN=64, 3 blocks/CU: grid (16, 8, 12) = 1536 = 2x768 exact ----
//   bz 0..7 : sent batch bz, col-tile bx (16 tiles of 64)
//   bz 8..11: tmpl batch (bz-8)*2 + (bx>>3), col-tile bx&7 (8 tiles of 64)
__global__ __launch_bounds__(256, 3)
void k_logits_all(const u16* __restrict__ Ah, const u16* __restrict__ Al,
                  const u16* __restrict__ sentBh, const u16* __restrict__ sentBl,
                  const u16* __restrict__ tmplBh, const u16* __restrict__ tmplBl,
                  float* __restrict__ sw, float* __restrict__ tw)
{
  __shared__ __align__(16) u16 ldsA[2 * SUB], ldsAl[2 * SUB];
  __shared__ __align__(16) u16 ldsB[2 * SUB64], ldsBl[2 * SUB64];
  int bx, by, bz;
  xcd_swz(bx, by, bz);
  const TC t = make_tc(threadIdx.x);

  const u16 *Bh, *Bl; float* Cf; int ldc, b, colTile;
  if (bz < 8) {
    b = bz; colTile = bx; Bh = sentBh; Bl = sentBl; Cf = sw; ldc = 1024;
  } else {
    b = (bz - 8) * 2 + (bx >> 3); colTile = bx & 7; Bh = tmplBh; Bl = tmplBl; Cf = tw; ldc = 512;
  }
  const size_t aoff = (size_t)b * (1024 * 1024) + (size_t)by * 128 * 1024;
  const size_t boff = (size_t)b * ((size_t)ldc * 1024) + (size_t)colTile * 64 * 1024;

  f32x4 acc[8];
#pragma unroll
  for (int i = 0; i < 8; ++i) acc[i] = f32x4{0.f, 0.f, 0.f, 0.f};

  pass32s64(acc, Ah + aoff, Al + aoff, 1024, Bh + boff, Bl + boff, 1024, 1024,
            ldsA, ldsAl, ldsB, ldsBl, t);

  const size_t cbse = (size_t)b * (1024 * (size_t)ldc);
  const int row0 = by * 128 + t.wm * 64;
  const int col0 = colTile * 64 + t.wn * 32;
  const int fq = ((threadIdx.x & 63) >> 4) * 4;
#pragma unroll
  for (int i = 0; i < 4; ++i)
#pragma unroll
    for (int j = 0; j < 2; ++j) {
      const int c = col0 + j * 16 + t.fr;
#pragma unroll
      for (int q = 0; q < 4; ++q)
        Cf[cbse + (size_t)(row0 + i * 16 + fq + q) * ldc + c] = acc[i * 2 + j][q];
    }
}

// ---- merged PV: grid (8, 8, 16) = 1024 = 2x512 exact; bz<8 sent, bz>=8 tmpl ----
__global__ __launch_bounds__(256, 2)
void k_pv_all(const u16* __restrict__ Ps, const u16* __restrict__ sentT,
              const u16* __restrict__ Pt, const u16* __restrict__ tmplT,
              u16* __restrict__ ctx_s, u16* __restrict__ ctx_t)
{
  __shared__ __align__(16) u16 ldsA[2 * 2 * SUB], ldsB[2 * 2 * SUB];
  int bx, by, bz;
  xcd_swz(bx, by, bz);
  const TC t = make_tc(threadIdx.x);

  const u16 *A, *Bt; u16* Cb; int ld, b;
  if (bz < 8) { b = bz; A = Ps; Bt = sentT; Cb = ctx_s; ld = 1024; }
  else        { b = bz - 8; A = Pt; Bt = tmplT; Cb = ctx_t; ld = 512; }

  f32x4 acc[16];
#pragma unroll
  for (int i = 0; i < 16; ++i) acc[i] = f32x4{0.f, 0.f, 0.f, 0.f};

  pass64(acc, A + (size_t)b * 1024 * ld + (size_t)by * 128 * ld, ld,
         Bt + (size_t)b * 1024 * ld + (size_t)bx * 128 * ld, ld, ld, ldsA, ldsB, t);

  const size_t cbse = (size_t)b * (1024 * 1024);
  const int row0 = by * 128 + t.wm * 64;
  const int col0 = bx * 128 + t.wn * 64;
  const int fq = ((threadIdx.x & 63) >> 4) * 4;
#pragma unroll
  for (int i = 0; i < 4; ++i)
#pragma unroll
    for (int j = 0; j < 4; ++j) {
      const int c = col0 + j * 16 + t.fr;
#pragma unroll
      for (int q = 0; q < 4; ++q)
        Cb[cbse + (size_t)(row0 + i * 16 + fq + q) * 1024 + c] = f2h(acc[i * 4 + j][q]);
    }
}

// ---- fusion4: 3 dual passes (round-11 proven) ----
__global__ __launch_bounds__(256, 2)
void k_fusion4(const u16* __restrict__ ctx_s, const u16* __restrict__ ctx_t,
               const u16* __restrict__ outh,
               const u16* __restrict__ Wg, const u16* __restrict__ Ws,
               const u16* __restrict__ Wt, const u16* __restrict__ Wo,
               float* __restrict__ fus)
{
  constexpr int H = 1024;
  __shared__ __align__(16) u16 ldsA[2 * SUB], ldsB0[2 * SUB], ldsB1[2 * SUB];  // 48 KB

  int bx, by, bz;
  xcd_swz(bx, by, bz);           // grid (8, 64, 1)
  const TC t = make_tc(threadIdx.x);

  const size_t aoff = (size_t)by * 128 * H;
  const size_t wgoff = (size_t)bx * 128 * (3 * H);
  const int row0 = by * 128 + t.wm * 64;
  const int col0 = bx * 128 + t.wn * 64;
  const int fq = ((threadIdx.x & 63) >> 4) * 4;

  f32x4 accZ[16], accW[16];
#pragma unroll
  for (int i = 0; i < 16; ++i) {
    accZ[i] = f32x4{0.f, 0.f, 0.f, 0.f};
    accW[i] = f32x4{0.f, 0.f, 0.f, 0.f};
  }

  // pass 0: A = ctx_s, B0 = Wg seg0, B1 = Ws
  pass32d(accZ, accW, ctx_s + aoff, H, Wg + wgoff, 3 * H,
          Ws + (size_t)bx * 128 * H, H, H, ldsA, ldsB0, ldsB1, t);
  f16x4 S16[16];
#pragma unroll
  for (int f = 0; f < 16; ++f) {
#pragma unroll
    for (int q = 0; q < 4; ++q) S16[f][q] = (_Float16)accW[f][q];
    accW[f] = f32x4{0.f, 0.f, 0.f, 0.f};
  }

  // pass 1: A = ctx_t, B0 = Wg seg1, B1 = Wt
  pass32d(accZ, accW, ctx_t + aoff, H, Wg + wgoff + H, 3 * H,
          Wt + (size_t)bx * 128 * H, H, H, ldsA, ldsB0, ldsB1, t);
  f16x4 T16[16];
#pragma unroll
  for (int f = 0; f < 16; ++f) {
#pragma unroll
    for (int q = 0; q < 4; ++q) T16[f][q] = (_Float16)accW[f][q];
    accW[f] = f32x4{0.f, 0.f, 0.f, 0.f};
  }

  // pass 2: A = outh, B0 = Wg seg2, B1 = Wo
  pass32d(accZ, accW, outh + aoff, H, Wg + wgoff + 2 * H, 3 * H,
          Wo + (size_t)bx * 128 * H, H, H, ldsA, ldsB0, ldsB1, t);

  // epilogue: g = sigmoid(z); fus = tanh(S + g*(T-S) + O)
#pragma unroll
  for (int i = 0; i < 4; ++i)
#pragma unroll
    for (int j = 0; j < 4; ++j) {
      const int f = i * 4 + j;
      const int c = col0 + j * 16 + t.fr;
#pragma unroll
      for (int q = 0; q < 4; ++q) {
        const int r = row0 + i * 16 + fq + q;
        const float g = 1.f / (1.f + __expf(-accZ[f][q]));
        const float sv = (float)S16[f][q];
        const float tv = (float)T16[f][q];
        float x = sv + g * (tv - sv) + accW[f][q];
        float ax = fabsf(x);
        float e = __expf(-2.f * ax);
        float th = (1.f - e) / (1.f + e);
        fus[(size_t)r * H + c] = copysignf(th, x);
      }
    }
}

extern "C" void kernel_launch(void* const* d_in, const int* in_sizes, int n_in,
                              void* d_out, int out_size, void* d_ws, size_t ws_size,
                              hipStream_t stream) {
  (void)in_sizes; (void)n_in; (void)out_size; (void)ws_size;
  constexpr int B = 8, T = 1024, S = 1024, St = 512, H = 1024;
  constexpr long long BTH = (long long)B * T * H;
  constexpr long long BSH = (long long)B * S * H;
  constexpr long long BStH = (long long)B * St * H;
  constexpr long long BTS = (long long)B * T * S;
  constexpr long long BTSt = (long long)B * T * St;

  const float* in_out  = (const float*)d_in[0];
  const float* in_sent = (const float*)d_in[1];
  const float* in_tmpl = (const float*)d_in[2];
  const float* in_Wg   = (const float*)d_in[3];
  const float* in_Ws   = (const float*)d_in[4];
  const float* in_Wt   = (const float*)d_in[5];
  const float* in_Wo   = (const float*)d_in[6];

  float* fus = (float*)d_out;         // (B,T,H)
  float* sw  = fus + BTH;             // (B,T,S)
  float* tw  = sw + BTS;              // (B,T,St)

  // ---- workspace ----
  char* p = (char*)d_ws;
  auto take = [&](long long bytes) { char* q = p; p += bytes; return q; };
  u16* out_h   = (u16*)take(BTH * 2);
  u16* out_lo  = (u16*)take(BTH * 2);
  u16* sent_h  = (u16*)take(BSH * 2);    // dead after logits -> reused as ctx_s
  u16* sent_lo = (u16*)take(BSH * 2);    // dead after logits -> reused as ctx_t
  u16* tmpl_h  = (u16*)take(BStH * 2);
  u16* tmpl_lo = (u16*)take(BStH * 2);
  u16* sentT   = (u16*)take(BSH * 2);    // (B,H,S)
  u16* tmplT   = (u16*)take(BStH * 2);   // (B,H,St)
  u16* Wg_h    = (u16*)take((long long)3 * H * H * 2);
  u16* Ws_h    = (u16*)take((long long)H * H * 2);
  u16* Wt_h    = (u16*)take((long long)H * H * 2);
  u16* Wo_h    = (u16*)take((long long)H * H * 2);
  u16* Ps      = (u16*)take(BTS * 2);
  u16* Pt      = (u16*)take(BTSt * 2);

  u16* ctx_s = sent_h;
  u16* ctx_t = sent_lo;

  dim3 thr(256);

  // 1: all conversions
  k_conv_all<<<dim3(32, 32, 16), dim3(32, 8), 0, stream>>>(
      in_out, in_sent, in_tmpl, in_Wg, in_Ws, in_Wt, in_Wo,
      out_h, out_lo, sent_h, sent_lo, sentT, tmpl_h, tmpl_lo, tmplT,
      Wg_h, Ws_h, Wt_h, Wo_h);

  // 2: both logits (3-pass split f16, BN=64, 3 blocks/CU) -> d_out weight slots
  k_logits_all<<<dim3(16, 8, 12), thr, 0, stream>>>(
      out_h, out_lo, sent_h, sent_lo, tmpl_h, tmpl_lo, sw, tw);

  // 3: both softmaxes (in place + f16 copy)
  k_softmax_all<<<4096, 256, 0, stream>>>(sw, Ps, tw, Pt);

  // 4: both PV GEMMs -> ctx (f16)
  k_pv_all<<<dim3(8, 8, 16), thr, 0, stream>>>(Ps, sentT, Pt, tmplT, ctx_s, ctx_t);

  // 5: fused gate + fusion (dual-B passes)
  k_fusion4<<<dim3(8, 64), thr, 0, stream>>>(
      ctx_s, ctx_t, out_h, Wg_h, Ws_h, Wt_h, Wo_h, fus);
}